// Round 2
// baseline (406.404 us; speedup 1.0000x reference)
//
#include <hip/hip_runtime.h>
#include <math.h>

#define N_NODES 50000
#define IN_CH   128
#define HEADS   4
#define HID     64
#define NEDGE   800000
#define EPS     1e-6f
#define LN_EPS  1e-5f
#define SCAN_T  1024

// ---------------- kernel A: degree histogram ------------------------
__global__ __launch_bounds__(256) void hist_kernel(const int* __restrict__ ei,
                                                   int* __restrict__ deg) {
    int e = blockIdx.x * 256 + threadIdx.x;
    if (e < NEDGE) atomicAdd(&deg[ei[e]], 1);
}

// ---------------- kernel B: prefix scan (1 block) + inv_w fused -----
__global__ __launch_bounds__(SCAN_T) void scan_kernel(const int* __restrict__ deg,
                                                      int* __restrict__ offsets,
                                                      int* __restrict__ cursor,
                                                      const float* __restrict__ bcos_w,
                                                      float* __restrict__ inv_w) {
    __shared__ int sums[SCAN_T];
    int tid = threadIdx.x;
    const int CH = (N_NODES + SCAN_T - 1) / SCAN_T;   // 49
    int base = tid * CH;
    int s = 0;
    for (int i = 0; i < CH; ++i) {
        int idx = base + i;
        if (idx < N_NODES) s += deg[idx];
    }
    sums[tid] = s;
    __syncthreads();
    // Hillis-Steele inclusive scan
    for (int off = 1; off < SCAN_T; off <<= 1) {
        int v = (tid >= off) ? sums[tid - off] : 0;
        __syncthreads();
        sums[tid] += v;
        __syncthreads();
    }
    int run = (tid == 0) ? 0 : sums[tid - 1];
    for (int i = 0; i < CH; ++i) {
        int idx = base + i;
        if (idx < N_NODES) { offsets[idx] = run; cursor[idx] = run; run += deg[idx]; }
    }
    if (tid == SCAN_T - 1) offsets[N_NODES] = sums[SCAN_T - 1];

    // fused: bcos_w row inverse norms
    if (tid < HID) {
        float ssw = 0.f;
#pragma unroll
        for (int k = 0; k < HID; ++k) {
            float v = bcos_w[tid * HID + k];
            ssw += v * v;
        }
        inv_w[tid] = 1.0f / fmaxf(sqrtf(ssw), 1e-12f);
    }
}

// ---------------- kernel C: CSR fill ---------------------------------
__global__ __launch_bounds__(256) void fill_kernel(const int* __restrict__ ei,
                                                   int* __restrict__ cursor,
                                                   int* __restrict__ csr_col) {
    int e = blockIdx.x * 256 + threadIdx.x;
    if (e < NEDGE) {
        int row = ei[e];
        int col = ei[NEDGE + e];
        int pos = atomicAdd(&cursor[row], 1);
        csr_col[pos] = col;
    }
}

// ---------------- kernel D: h = x @ lin_w.T + per-head inv norms -----
// 4 waves/block, 4 nodes per wave (w-read amortized over 4 nodes)
__global__ __launch_bounds__(256) void h_kernel(const float* __restrict__ x,
                                                const float* __restrict__ lin_w,
                                                float* __restrict__ h,
                                                float* __restrict__ inv_hn) {
    __shared__ float4 w4[HID][IN_CH / 4 + 1];    // stride 33 f4: conflict-free b128
    __shared__ float4 xs4[16][IN_CH / 4];        // 16 nodes x 32 f4

    const float4* w4g = (const float4*)lin_w;
    for (int i = threadIdx.x; i < HID * (IN_CH / 4); i += 256)
        w4[i >> 5][i & 31] = w4g[i];

    int nb = blockIdx.x * 16;
    const float4* x4 = (const float4*)x;
    for (int i = threadIdx.x; i < 16 * (IN_CH / 4); i += 256) {
        int nn = nb + (i >> 5);
        xs4[i >> 5][i & 31] = x4[(size_t)nn * (IN_CH / 4) + (i & 31)];
    }
    __syncthreads();

    int wave = threadIdx.x >> 6;
    int c    = threadIdx.x & 63;
    int n0   = wave * 4;                         // local node base

    float a0 = 0.f, a1 = 0.f, a2 = 0.f, a3 = 0.f;
#pragma unroll
    for (int k4 = 0; k4 < IN_CH / 4; ++k4) {
        float4 wv = w4[c][k4];
        float4 x0 = xs4[n0 + 0][k4];
        float4 x1 = xs4[n0 + 1][k4];
        float4 x2 = xs4[n0 + 2][k4];
        float4 x3 = xs4[n0 + 3][k4];
        a0 += wv.x * x0.x + wv.y * x0.y + wv.z * x0.z + wv.w * x0.w;
        a1 += wv.x * x1.x + wv.y * x1.y + wv.z * x1.z + wv.w * x1.w;
        a2 += wv.x * x2.x + wv.y * x2.y + wv.z * x2.z + wv.w * x2.w;
        a3 += wv.x * x3.x + wv.y * x3.y + wv.z * x3.z + wv.w * x3.w;
    }

    float accs[4] = {a0, a1, a2, a3};
#pragma unroll
    for (int j = 0; j < 4; ++j) {
        int node = nb + n0 + j;
        h[(size_t)node * HID + c] = accs[j];
        float ss = accs[j] * accs[j];
        ss += __shfl_xor(ss, 1);
        ss += __shfl_xor(ss, 2);
        ss += __shfl_xor(ss, 4);
        ss += __shfl_xor(ss, 8);
        if ((c & 15) == 0)
            inv_hn[node * HEADS + (c >> 4)] = 1.0f / fmaxf(sqrtf(ss), 1e-12f);
    }
}

// ---------------- kernel E: gather + bcos linear + layernorm ---------
// one wave per node; full out-row lives in the wave -> epilogue fused
__global__ __launch_bounds__(256) void gather_final(const int* __restrict__ offsets,
                                                    const int* __restrict__ csr_col,
                                                    const float* __restrict__ h,
                                                    const float* __restrict__ inv_hn,
                                                    const float* __restrict__ bcos_w,
                                                    const float* __restrict__ inv_w_g,
                                                    const float* __restrict__ gamma,
                                                    const float* __restrict__ beta,
                                                    float* __restrict__ y) {
    __shared__ float w[HID][HID + 1];            // padded: conflict-free
    __shared__ float ivw[HID], gm[HID], bt[HID];

    for (int i = threadIdx.x; i < HID * HID; i += 256)
        w[i >> 6][i & 63] = bcos_w[i];
    if (threadIdx.x < HID) {
        ivw[threadIdx.x] = inv_w_g[threadIdx.x];
        gm[threadIdx.x]  = gamma[threadIdx.x];
        bt[threadIdx.x]  = beta[threadIdx.x];
    }
    __syncthreads();

    int grp  = threadIdx.x >> 6;
    int lane = threadIdx.x & 63;
    int head = lane >> 4;
    int node = blockIdx.x * 4 + grp;
    if (node >= N_NODES) return;

    float hr  = h[(size_t)node * HID + lane];
    float ihr = inv_hn[node * HEADS + head];
    int start = offsets[node];
    int end   = offsets[node + 1];

    float acc = 0.f;
    for (int base = start; base < end; base += 64) {
        int n = min(64, end - base);
        int vcol = (lane < n) ? csr_col[base + lane] : 0;
#pragma unroll 2
        for (int k = 0; k < n; ++k) {
            int col   = __shfl(vcol, k);
            float hc  = h[(size_t)col * HID + lane];
            float ihc = inv_hn[col * HEADS + head];
            float p = hc * hr;
            p += __shfl_xor(p, 1);
            p += __shfl_xor(p, 2);
            p += __shfl_xor(p, 4);
            p += __shfl_xor(p, 8);
            float cosv = p * ihc * ihr;
            cosv = fminf(fmaxf(cosv, EPS), 1.0f);   // B_EXP=2 -> scale == cos
            acc = fmaf(hc, cosv, acc);
        }
    }

    // ||out_row||
    float ss = acc * acc;
    ss += __shfl_xor(ss, 1);
    ss += __shfl_xor(ss, 2);
    ss += __shfl_xor(ss, 4);
    ss += __shfl_xor(ss, 8);
    ss += __shfl_xor(ss, 16);
    ss += __shfl_xor(ss, 32);
    float inv_no = 1.0f / fmaxf(sqrtf(ss), 1e-12f);

    // lin[lane] = dot(out_row, bcos_w[lane,:]) via readlane broadcasts
    float lin = 0.f;
#pragma unroll
    for (int k = 0; k < HID; ++k)
        lin = fmaf(__shfl(acc, k), w[lane][k], lin);

    float c2 = lin * inv_no * ivw[lane];
    c2 = fminf(fmaxf(c2, EPS), 1.0f);
    float ob = lin * c2;

    // LayerNorm over 64 lanes
    float mu = ob;
    mu += __shfl_xor(mu, 1);
    mu += __shfl_xor(mu, 2);
    mu += __shfl_xor(mu, 4);
    mu += __shfl_xor(mu, 8);
    mu += __shfl_xor(mu, 16);
    mu += __shfl_xor(mu, 32);
    mu *= (1.0f / 64.0f);

    float d = ob - mu;
    float var = d * d;
    var += __shfl_xor(var, 1);
    var += __shfl_xor(var, 2);
    var += __shfl_xor(var, 4);
    var += __shfl_xor(var, 8);
    var += __shfl_xor(var, 16);
    var += __shfl_xor(var, 32);
    var *= (1.0f / 64.0f);

    float r = rsqrtf(var + LN_EPS);
    y[(size_t)node * HID + lane] = d * r * gm[lane] + bt[lane];
}

// ---------------------------------------------------------------------
extern "C" void kernel_launch(void* const* d_in, const int* in_sizes, int n_in,
                              void* d_out, int out_size, void* d_ws, size_t ws_size,
                              hipStream_t stream) {
    const float* x      = (const float*)d_in[0];
    const int*   ei     = (const int*)d_in[1];
    const float* lin_w  = (const float*)d_in[2];
    const float* bcos_w = (const float*)d_in[3];
    const float* gamma  = (const float*)d_in[4];
    const float* beta   = (const float*)d_in[5];
    float*       y      = (float*)d_out;

    // workspace layout
    float* h       = (float*)d_ws;                          // N*64 f
    float* inv_hn  = h + (size_t)N_NODES * HID;             // N*4 f
    float* inv_w   = inv_hn + (size_t)N_NODES * HEADS;      // 64 f
    int*   deg     = (int*)(inv_w + HID);                   // N i
    int*   offsets = deg + N_NODES;                         // N+1 i
    int*   cursor  = offsets + N_NODES + 1;                 // N i
    int*   csr_col = cursor + N_NODES;                      // E i

    hipMemsetAsync(deg, 0, N_NODES * sizeof(int), stream);

    h_kernel<<<N_NODES / 16, 256, 0, stream>>>(x, lin_w, h, inv_hn);

    hist_kernel<<<(NEDGE + 255) / 256, 256, 0, stream>>>(ei, deg);

    scan_kernel<<<1, SCAN_T, 0, stream>>>(deg, offsets, cursor, bcos_w, inv_w);

    fill_kernel<<<(NEDGE + 255) / 256, 256, 0, stream>>>(ei, cursor, csr_col);

    gather_final<<<(N_NODES + 3) / 4, 256, 0, stream>>>(offsets, csr_col, h, inv_hn,
                                                        bcos_w, inv_w, gamma, beta, y);
}

// Round 3
// 239.792 us; speedup vs baseline: 1.6948x; 1.6948x over previous
//
#include <hip/hip_runtime.h>
#include <math.h>

#define N_NODES 50000
#define IN_CH   128
#define HEADS   4
#define HID     64
#define NEDGE   800000
#define EPS     1e-6f
#define LN_EPS  1e-5f

#define REDUCE16(p) { p += __shfl_xor(p,1); p += __shfl_xor(p,2); \
                      p += __shfl_xor(p,4); p += __shfl_xor(p,8); }
#define REDUCE64(p) { p += __shfl_xor(p,1); p += __shfl_xor(p,2); \
                      p += __shfl_xor(p,4); p += __shfl_xor(p,8); \
                      p += __shfl_xor(p,16); p += __shfl_xor(p,32); }

// ---------------- kernel A: degree histogram ------------------------
__global__ __launch_bounds__(256) void hist_kernel(const int* __restrict__ ei,
                                                   int* __restrict__ deg) {
    int e = blockIdx.x * 256 + threadIdx.x;
    if (e < NEDGE) atomicAdd(&deg[ei[e]], 1);
}

// ---------------- kernel B1: per-1024-chunk partial sums + inv_w -----
__global__ __launch_bounds__(1024) void partial_kernel(const int* __restrict__ deg,
                                                       int* __restrict__ partial,
                                                       const float* __restrict__ bcos_w,
                                                       float* __restrict__ inv_w) {
    __shared__ int wsum[16];
    int tid = threadIdx.x, lane = tid & 63, w = tid >> 6;
    int i = blockIdx.x * 1024 + tid;
    int v = (i < N_NODES) ? deg[i] : 0;
    REDUCE64(v);
    if (lane == 0) wsum[w] = v;
    __syncthreads();
    if (w == 0) {
        int t = (lane < 16) ? wsum[lane] : 0;
        REDUCE16(t);
        if (lane == 0) partial[blockIdx.x] = t;
    }
    // fused: bcos_w row inverse norms (one spare wave of block 0)
    if (blockIdx.x == 0 && w == 15) {
        int j = lane;
        const float4* w4 = (const float4*)bcos_w;
        float ss = 0.f;
#pragma unroll
        for (int k4 = 0; k4 < HID / 4; ++k4) {
            float4 q = w4[j * (HID / 4) + k4];
            ss += q.x * q.x + q.y * q.y + q.z * q.z + q.w * q.w;
        }
        inv_w[j] = 1.0f / fmaxf(sqrtf(ss), 1e-12f);
    }
}

// ---------------- kernel B2: block-scan -> offsets + cursor ----------
__global__ __launch_bounds__(1024) void offsets_kernel(const int* __restrict__ deg,
                                                       const int* __restrict__ partial,
                                                       int* __restrict__ offsets,
                                                       int* __restrict__ cursor) {
    __shared__ int wsum[16];
    __shared__ int bbase_s;
    int tid = threadIdx.x, lane = tid & 63, w = tid >> 6;
    int b = blockIdx.x;

    if (tid < 64) {                       // block base = sum of preceding partials
        int v = (lane < b) ? partial[lane] : 0;
        REDUCE64(v);
        if (lane == 0) bbase_s = v;
    }

    int i = b * 1024 + tid;
    int val = (i < N_NODES) ? deg[i] : 0;
    int s = val;                          // wave inclusive scan
#pragma unroll
    for (int off = 1; off < 64; off <<= 1) {
        int t = __shfl_up(s, off);
        if (lane >= off) s += t;
    }
    if (lane == 63) wsum[w] = s;
    __syncthreads();
    if (w == 0 && lane < 16) {            // scan the 16 wave totals
        int t = wsum[lane];
#pragma unroll
        for (int off = 1; off < 16; off <<= 1) {
            int u = __shfl_up(t, off);
            if (lane >= off) t += u;
        }
        wsum[lane] = t;
    }
    __syncthreads();
    int incl = bbase_s + ((w == 0) ? 0 : wsum[w - 1]) + s;
    if (i < N_NODES) {
        offsets[i] = incl - val;
        cursor[i]  = incl - val;
    }
    if (b == gridDim.x - 1 && tid == 1023) offsets[N_NODES] = incl;
}

// ---------------- kernel C: CSR fill ---------------------------------
__global__ __launch_bounds__(256) void fill_kernel(const int* __restrict__ ei,
                                                   int* __restrict__ cursor,
                                                   int* __restrict__ csr_col) {
    int e = blockIdx.x * 256 + threadIdx.x;
    if (e < NEDGE) {
        int row = ei[e];
        int col = ei[NEDGE + e];
        int pos = atomicAdd(&cursor[row], 1);
        csr_col[pos] = col;
    }
}

// ---------------- kernel D: h = x @ lin_w.T + per-head inv norms -----
// 4 waves/block, 4 nodes/wave. w transposed in LDS (stride-65 f4,
// conflict-free b128); x via scalar (readfirstlane) base -> s_load.
__global__ __launch_bounds__(256) void h_kernel(const float* __restrict__ x,
                                                const float* __restrict__ lin_w,
                                                float* __restrict__ h,
                                                float* __restrict__ inv_hn) {
    __shared__ float4 wt[32 * 65];               // [k4][c], stride 65
    const float4* w4g = (const float4*)lin_w;    // [c][k4]
    for (int i = threadIdx.x; i < HID * (IN_CH / 4); i += 256) {
        int c = i >> 5, k4 = i & 31;
        wt[k4 * 65 + c] = w4g[i];                // global read fully coalesced
    }
    __syncthreads();

    int wave = threadIdx.x >> 6;
    int lane = threadIdx.x & 63;
    int n0 = __builtin_amdgcn_readfirstlane(blockIdx.x * 16 + wave * 4);
    const float4* xp = (const float4*)x;

    float a0 = 0.f, a1 = 0.f, a2 = 0.f, a3 = 0.f;
#pragma unroll 2
    for (int k4 = 0; k4 < IN_CH / 4; ++k4) {
        float4 wv = wt[k4 * 65 + lane];
        float4 x0 = xp[(n0 + 0) * 32 + k4];      // uniform -> scalar loads
        float4 x1 = xp[(n0 + 1) * 32 + k4];
        float4 x2 = xp[(n0 + 2) * 32 + k4];
        float4 x3 = xp[(n0 + 3) * 32 + k4];
        a0 += wv.x * x0.x + wv.y * x0.y + wv.z * x0.z + wv.w * x0.w;
        a1 += wv.x * x1.x + wv.y * x1.y + wv.z * x1.z + wv.w * x1.w;
        a2 += wv.x * x2.x + wv.y * x2.y + wv.z * x2.z + wv.w * x2.w;
        a3 += wv.x * x3.x + wv.y * x3.y + wv.z * x3.z + wv.w * x3.w;
    }

    float accs[4] = {a0, a1, a2, a3};
#pragma unroll
    for (int j = 0; j < 4; ++j) {
        int node = n0 + j;
        h[node * HID + lane] = accs[j];
        float ss = accs[j] * accs[j];
        REDUCE16(ss);
        if ((lane & 15) == 0)
            inv_hn[node * HEADS + (lane >> 4)] = 1.0f / fmaxf(sqrtf(ss), 1e-12f);
    }
}

// ---------------- kernel E: gather (ILP-4) + bcos linear + layernorm -
__global__ __launch_bounds__(256) void gather_final(const int* __restrict__ offsets,
                                                    const int* __restrict__ csr_col,
                                                    const float* __restrict__ h,
                                                    const float* __restrict__ inv_hn,
                                                    const float* __restrict__ bcos_w,
                                                    const float* __restrict__ inv_w_g,
                                                    const float* __restrict__ gamma,
                                                    const float* __restrict__ beta,
                                                    float* __restrict__ y) {
    __shared__ float w[HID][HID + 1];
    __shared__ float ivw[HID], gm[HID], bt[HID];

    for (int i = threadIdx.x; i < HID * HID; i += 256)
        w[i >> 6][i & 63] = bcos_w[i];
    if (threadIdx.x < HID) {
        ivw[threadIdx.x] = inv_w_g[threadIdx.x];
        gm[threadIdx.x]  = gamma[threadIdx.x];
        bt[threadIdx.x]  = beta[threadIdx.x];
    }
    __syncthreads();

    int grp  = threadIdx.x >> 6;
    int lane = threadIdx.x & 63;
    int head = lane >> 4;
    int node = blockIdx.x * 4 + grp;

    float hr  = h[node * HID + lane];
    float ihr = inv_hn[node * HEADS + head];
    int start = __builtin_amdgcn_readfirstlane(offsets[node]);
    int end   = __builtin_amdgcn_readfirstlane(offsets[node + 1]);

    float a0 = 0.f, a1 = 0.f, a2 = 0.f, a3 = 0.f;
    int b = start;
#pragma unroll 1
    for (; b + 4 <= end; b += 4) {
        int c0 = csr_col[b + 0];
        int c1 = csr_col[b + 1];
        int c2 = csr_col[b + 2];
        int c3 = csr_col[b + 3];
        float h0 = h[c0 * HID + lane];
        float h1 = h[c1 * HID + lane];
        float h2 = h[c2 * HID + lane];
        float h3 = h[c3 * HID + lane];
        float i0 = inv_hn[c0 * HEADS + head];
        float i1 = inv_hn[c1 * HEADS + head];
        float i2 = inv_hn[c2 * HEADS + head];
        float i3 = inv_hn[c3 * HEADS + head];
        float p0 = h0 * hr, p1 = h1 * hr, p2 = h2 * hr, p3 = h3 * hr;
        REDUCE16(p0); REDUCE16(p1); REDUCE16(p2); REDUCE16(p3);
        float s0 = fminf(fmaxf(p0 * i0 * ihr, EPS), 1.0f);
        float s1 = fminf(fmaxf(p1 * i1 * ihr, EPS), 1.0f);
        float s2 = fminf(fmaxf(p2 * i2 * ihr, EPS), 1.0f);
        float s3 = fminf(fmaxf(p3 * i3 * ihr, EPS), 1.0f);
        a0 = fmaf(h0, s0, a0);
        a1 = fmaf(h1, s1, a1);
        a2 = fmaf(h2, s2, a2);
        a3 = fmaf(h3, s3, a3);
    }
    for (; b < end; ++b) {                        // tail (<=3 edges)
        int c0 = csr_col[b];
        float h0 = h[c0 * HID + lane];
        float i0 = inv_hn[c0 * HEADS + head];
        float p0 = h0 * hr;
        REDUCE16(p0);
        float s0 = fminf(fmaxf(p0 * i0 * ihr, EPS), 1.0f);
        a0 = fmaf(h0, s0, a0);
    }
    float acc = (a0 + a1) + (a2 + a3);

    // ||out_row||
    float ss = acc * acc;
    REDUCE64(ss);
    float inv_no = 1.0f / fmaxf(sqrtf(ss), 1e-12f);

    // lin[lane] = dot(out_row, bcos_w[lane,:])
    float lin = 0.f;
#pragma unroll
    for (int k = 0; k < HID; ++k)
        lin = fmaf(__shfl(acc, k), w[lane][k], lin);

    float c2v = lin * inv_no * ivw[lane];
    c2v = fminf(fmaxf(c2v, EPS), 1.0f);
    float ob = lin * c2v;                         // B_EXP=2 -> cos2**1

    // LayerNorm over 64 lanes
    float mu = ob;
    REDUCE64(mu);
    mu *= (1.0f / 64.0f);
    float d = ob - mu;
    float var = d * d;
    REDUCE64(var);
    var *= (1.0f / 64.0f);
    float r = rsqrtf(var + LN_EPS);
    y[node * HID + lane] = d * r * gm[lane] + bt[lane];
}

// ---------------------------------------------------------------------
extern "C" void kernel_launch(void* const* d_in, const int* in_sizes, int n_in,
                              void* d_out, int out_size, void* d_ws, size_t ws_size,
                              hipStream_t stream) {
    const float* x      = (const float*)d_in[0];
    const int*   ei     = (const int*)d_in[1];
    const float* lin_w  = (const float*)d_in[2];
    const float* bcos_w = (const float*)d_in[3];
    const float* gamma  = (const float*)d_in[4];
    const float* beta   = (const float*)d_in[5];
    float*       y      = (float*)d_out;

    // workspace layout
    float* h       = (float*)d_ws;                          // N*64 f
    float* inv_hn  = h + (size_t)N_NODES * HID;             // N*4 f
    float* inv_w   = inv_hn + (size_t)N_NODES * HEADS;      // 64 f
    int*   deg     = (int*)(inv_w + HID);                   // N i
    int*   partial = deg + N_NODES;                         // 64 i
    int*   offsets = partial + 64;                          // N+1 i
    int*   cursor  = offsets + N_NODES + 1;                 // N i
    int*   csr_col = cursor + N_NODES;                      // E i

    const int SCAN_BLOCKS = (N_NODES + 1023) / 1024;        // 49

    hipMemsetAsync(deg, 0, N_NODES * sizeof(int), stream);

    h_kernel<<<N_NODES / 16, 256, 0, stream>>>(x, lin_w, h, inv_hn);

    hist_kernel<<<(NEDGE + 255) / 256, 256, 0, stream>>>(ei, deg);

    partial_kernel<<<SCAN_BLOCKS, 1024, 0, stream>>>(deg, partial, bcos_w, inv_w);

    offsets_kernel<<<SCAN_BLOCKS, 1024, 0, stream>>>(deg, partial, offsets, cursor);

    fill_kernel<<<(NEDGE + 255) / 256, 256, 0, stream>>>(ei, cursor, csr_col);

    gather_final<<<N_NODES / 4, 256, 0, stream>>>(offsets, csr_col, h, inv_hn,
                                                  bcos_w, inv_w, gamma, beta, y);
}

// Round 4
// 195.604 us; speedup vs baseline: 2.0777x; 1.2259x over previous
//
#include <hip/hip_runtime.h>
#include <math.h>

#define N_NODES 50000
#define IN_CH   128
#define HEADS   4
#define HID     64
#define NEDGE   800000
#define EPS     1e-6f
#define LN_EPS  1e-5f

// ---- cross-lane reduce helpers --------------------------------------
// 16-lane butterfly sum via DPP: xor masks {1,2,7,15} generate the 16-group.
// quad_perm[1,0,3,2]=0xB1 (xor1), quad_perm[2,3,0,1]=0x4E (xor2),
// row_half_mirror=0x141 (xor7), row_mirror=0x140 (xor15).
#define DPP_ADD_F(p, ctrl) \
    p += __int_as_float(__builtin_amdgcn_update_dpp(0, __float_as_int(p), ctrl, 0xF, 0xF, true))
#define REDUCE16_DPP(p) { DPP_ADD_F(p,0xB1); DPP_ADD_F(p,0x4E); \
                          DPP_ADD_F(p,0x141); DPP_ADD_F(p,0x140); }

#define REDUCE16(p) { p += __shfl_xor(p,1); p += __shfl_xor(p,2); \
                      p += __shfl_xor(p,4); p += __shfl_xor(p,8); }
#define REDUCE64(p) { REDUCE16_DPP(p); p += __shfl_xor(p,16); p += __shfl_xor(p,32); }
#define REDUCE64I(p) { p += __shfl_xor(p,1); p += __shfl_xor(p,2); \
                       p += __shfl_xor(p,4); p += __shfl_xor(p,8); \
                       p += __shfl_xor(p,16); p += __shfl_xor(p,32); }

// ---------------- kernel A: degree histogram (int4) ------------------
__global__ __launch_bounds__(256) void hist_kernel(const int* __restrict__ ei,
                                                   int* __restrict__ deg) {
    int t = blockIdx.x * 256 + threadIdx.x;
    if (t < NEDGE / 4) {
        int4 r = ((const int4*)ei)[t];
        atomicAdd(&deg[r.x], 1);
        atomicAdd(&deg[r.y], 1);
        atomicAdd(&deg[r.z], 1);
        atomicAdd(&deg[r.w], 1);
    }
}

// ---------------- kernel B1: per-1024-chunk partial sums + inv_w -----
__global__ __launch_bounds__(1024) void partial_kernel(const int* __restrict__ deg,
                                                       int* __restrict__ partial,
                                                       const float* __restrict__ bcos_w,
                                                       float* __restrict__ inv_w) {
    __shared__ int wsum[16];
    int tid = threadIdx.x, lane = tid & 63, w = tid >> 6;
    int i = blockIdx.x * 1024 + tid;
    int v = (i < N_NODES) ? deg[i] : 0;
    REDUCE64I(v);
    if (lane == 0) wsum[w] = v;
    __syncthreads();
    if (w == 0) {
        int t = (lane < 16) ? wsum[lane] : 0;
        REDUCE16(t);
        if (lane == 0) partial[blockIdx.x] = t;
    }
    if (blockIdx.x == 0 && w == 15) {      // fused: bcos_w row inverse norms
        int j = lane;
        const float4* w4 = (const float4*)bcos_w;
        float ss = 0.f;
#pragma unroll
        for (int k4 = 0; k4 < HID / 4; ++k4) {
            float4 q = w4[j * (HID / 4) + k4];
            ss += q.x * q.x + q.y * q.y + q.z * q.z + q.w * q.w;
        }
        inv_w[j] = 1.0f / fmaxf(sqrtf(ss), 1e-12f);
    }
}

// ---------------- kernel B2: block-scan -> offsets + cursor ----------
__global__ __launch_bounds__(1024) void offsets_kernel(const int* __restrict__ deg,
                                                       const int* __restrict__ partial,
                                                       int* __restrict__ offsets,
                                                       int* __restrict__ cursor) {
    __shared__ int wsum[16];
    __shared__ int bbase_s;
    int tid = threadIdx.x, lane = tid & 63, w = tid >> 6;
    int b = blockIdx.x;

    if (tid < 64) {
        int v = (lane < b) ? partial[lane] : 0;
        REDUCE64I(v);
        if (lane == 0) bbase_s = v;
    }

    int i = b * 1024 + tid;
    int val = (i < N_NODES) ? deg[i] : 0;
    int s = val;
#pragma unroll
    for (int off = 1; off < 64; off <<= 1) {
        int t = __shfl_up(s, off);
        if (lane >= off) s += t;
    }
    if (lane == 63) wsum[w] = s;
    __syncthreads();
    if (w == 0 && lane < 16) {
        int t = wsum[lane];
#pragma unroll
        for (int off = 1; off < 16; off <<= 1) {
            int u = __shfl_up(t, off);
            if (lane >= off) t += u;
        }
        wsum[lane] = t;
    }
    __syncthreads();
    int incl = bbase_s + ((w == 0) ? 0 : wsum[w - 1]) + s;
    if (i < N_NODES) {
        offsets[i] = incl - val;
        cursor[i]  = incl - val;
    }
    if (b == gridDim.x - 1 && tid == 1023) offsets[N_NODES] = incl;
}

// ---------------- kernel C: CSR fill (int4) ---------------------------
__global__ __launch_bounds__(256) void fill_kernel(const int* __restrict__ ei,
                                                   int* __restrict__ cursor,
                                                   int* __restrict__ csr_col) {
    int t = blockIdx.x * 256 + threadIdx.x;
    if (t < NEDGE / 4) {
        int4 r = ((const int4*)ei)[t];
        int4 c = ((const int4*)(ei + NEDGE))[t];
        csr_col[atomicAdd(&cursor[r.x], 1)] = c.x;
        csr_col[atomicAdd(&cursor[r.y], 1)] = c.y;
        csr_col[atomicAdd(&cursor[r.z], 1)] = c.z;
        csr_col[atomicAdd(&cursor[r.w], 1)] = c.w;
    }
}

// ---------------- kernel D: h = x @ lin_w.T + inv norms + deg=0 ------
__global__ __launch_bounds__(256) void h_kernel(const float* __restrict__ x,
                                                const float* __restrict__ lin_w,
                                                float* __restrict__ h,
                                                float* __restrict__ inv_hn,
                                                int* __restrict__ deg) {
    __shared__ float4 wt[32 * 65];               // [k4][c], lane-contiguous
    const float4* w4g = (const float4*)lin_w;    // [c][k4]
    for (int i = threadIdx.x; i < HID * (IN_CH / 4); i += 256) {
        int c = i >> 5, k4 = i & 31;
        wt[k4 * 65 + c] = w4g[i];
    }
    __syncthreads();

    int wave = threadIdx.x >> 6;
    int lane = threadIdx.x & 63;
    const float4* xp = (const float4*)x;

    for (int g = blockIdx.x; g < N_NODES / 16; g += gridDim.x) {
        int n0 = __builtin_amdgcn_readfirstlane(g * 16 + wave * 4);
        if (lane < 4) deg[n0 + lane] = 0;

        float a0 = 0.f, a1 = 0.f, a2 = 0.f, a3 = 0.f;
#pragma unroll 2
        for (int k4 = 0; k4 < IN_CH / 4; ++k4) {
            float4 wv = wt[k4 * 65 + lane];
            float4 x0 = xp[(n0 + 0) * 32 + k4];  // uniform -> s_load
            float4 x1 = xp[(n0 + 1) * 32 + k4];
            float4 x2 = xp[(n0 + 2) * 32 + k4];
            float4 x3 = xp[(n0 + 3) * 32 + k4];
            a0 += wv.x * x0.x + wv.y * x0.y + wv.z * x0.z + wv.w * x0.w;
            a1 += wv.x * x1.x + wv.y * x1.y + wv.z * x1.z + wv.w * x1.w;
            a2 += wv.x * x2.x + wv.y * x2.y + wv.z * x2.z + wv.w * x2.w;
            a3 += wv.x * x3.x + wv.y * x3.y + wv.z * x3.z + wv.w * x3.w;
        }

        float accs[4] = {a0, a1, a2, a3};
#pragma unroll
        for (int j = 0; j < 4; ++j) {
            int node = n0 + j;
            h[node * HID + lane] = accs[j];
            float ss = accs[j] * accs[j];
            REDUCE16_DPP(ss);
            if ((lane & 15) == 0)
                inv_hn[node * HEADS + (lane >> 4)] = 1.0f / fmaxf(sqrtf(ss), 1e-12f);
        }
    }
}

// ---------------- kernel E: gather (DPP, ILP-8) + bcos + layernorm ---
__global__ __launch_bounds__(256) void gather_final(const int* __restrict__ offsets,
                                                    const int* __restrict__ csr_col,
                                                    const float* __restrict__ h,
                                                    const float* __restrict__ inv_hn,
                                                    const float* __restrict__ bcos_w,
                                                    const float* __restrict__ inv_w_g,
                                                    const float* __restrict__ gamma,
                                                    const float* __restrict__ beta,
                                                    float* __restrict__ y) {
    __shared__ float4 wt4[16][64];               // [k4][j]: lane-contiguous b128
    __shared__ float rowbuf[4][HID];
    __shared__ float ivw[HID], gm[HID], bt[HID];

    for (int i = threadIdx.x; i < HID * (HID / 4); i += 256) {
        int j = i >> 4, k4 = i & 15;
        wt4[k4][j] = ((const float4*)bcos_w)[i];
    }
    if (threadIdx.x < HID) {
        ivw[threadIdx.x] = inv_w_g[threadIdx.x];
        gm[threadIdx.x]  = gamma[threadIdx.x];
        bt[threadIdx.x]  = beta[threadIdx.x];
    }
    __syncthreads();

    int grp  = threadIdx.x >> 6;
    int lane = threadIdx.x & 63;
    int head = lane >> 4;

    for (int g = blockIdx.x; g < N_NODES / 4; g += gridDim.x) {
        int node = g * 4 + grp;
        float hr  = h[node * HID + lane];
        float ihr = inv_hn[node * HEADS + head];
        float hrs = hr * ihr;
        int start = __builtin_amdgcn_readfirstlane(offsets[node]);
        int end   = __builtin_amdgcn_readfirstlane(offsets[node + 1]);

        float ac0 = 0.f, ac1 = 0.f, ac2 = 0.f, ac3 = 0.f;
        int b = start;
#pragma unroll 1
        for (; b + 8 <= end; b += 8) {
            int   cc[8]; float hh[8], ii[8];
#pragma unroll
            for (int j = 0; j < 8; ++j) cc[j] = csr_col[b + j];       // s_load
#pragma unroll
            for (int j = 0; j < 8; ++j) hh[j] = h[cc[j] * HID + lane];
#pragma unroll
            for (int j = 0; j < 8; ++j) ii[j] = inv_hn[cc[j] * HEADS + head];
#pragma unroll
            for (int j = 0; j < 8; ++j) {
                float p = hh[j] * hrs;
                REDUCE16_DPP(p);
                float s = fminf(fmaxf(p * ii[j], EPS), 1.0f);   // med3
                if (j == 0) ac0 = fmaf(hh[j], s, ac0);
                else if (j == 1) ac1 = fmaf(hh[j], s, ac1);
                else if (j == 2) ac2 = fmaf(hh[j], s, ac2);
                else if (j == 3) ac3 = fmaf(hh[j], s, ac3);
                else if (j == 4) ac0 = fmaf(hh[j], s, ac0);
                else if (j == 5) ac1 = fmaf(hh[j], s, ac1);
                else if (j == 6) ac2 = fmaf(hh[j], s, ac2);
                else             ac3 = fmaf(hh[j], s, ac3);
            }
        }
        int k = end - b;
        if (k > 0) {                          // masked 8-wide tail (uniform)
            int   cc[8]; float hh[8], ii[8];
#pragma unroll
            for (int j = 0; j < 8; ++j) cc[j] = csr_col[(j < k) ? (b + j) : (end - 1)];
#pragma unroll
            for (int j = 0; j < 8; ++j) hh[j] = h[cc[j] * HID + lane];
#pragma unroll
            for (int j = 0; j < 8; ++j) ii[j] = inv_hn[cc[j] * HEADS + head];
#pragma unroll
            for (int j = 0; j < 8; ++j) {
                float p = hh[j] * hrs;
                REDUCE16_DPP(p);
                float s = fminf(fmaxf(p * ii[j], EPS), 1.0f);
                s = (j < k) ? s : 0.0f;
                if (j & 1) ac1 = fmaf(hh[j], s, ac1);
                else       ac0 = fmaf(hh[j], s, ac0);
            }
        }
        float acc = (ac0 + ac1) + (ac2 + ac3);

        // ---- fused epilogue: bcos linear + layernorm ----
        rowbuf[grp][lane] = acc;              // per-wave private, no barrier
        float ss = acc * acc;
        REDUCE64(ss);
        float inv_no = 1.0f / fmaxf(sqrtf(ss), 1e-12f);

        const float4* rb4 = (const float4*)rowbuf[grp];
        float lin = 0.f;
#pragma unroll
        for (int k4 = 0; k4 < 16; ++k4) {
            float4 a  = rb4[k4];              // broadcast read
            float4 wv = wt4[k4][lane];        // contiguous b128
            lin += a.x * wv.x + a.y * wv.y + a.z * wv.z + a.w * wv.w;
        }

        float c2v = lin * inv_no * ivw[lane];
        c2v = fminf(fmaxf(c2v, EPS), 1.0f);
        float ob = lin * c2v;                 // B_EXP=2 -> cos2**1

        float mu = ob;
        REDUCE64(mu);
        mu *= (1.0f / 64.0f);
        float d = ob - mu;
        float var = d * d;
        REDUCE64(var);
        var *= (1.0f / 64.0f);
        float r = rsqrtf(var + LN_EPS);
        y[node * HID + lane] = d * r * gm[lane] + bt[lane];
    }
}

// ---------------------------------------------------------------------
extern "C" void kernel_launch(void* const* d_in, const int* in_sizes, int n_in,
                              void* d_out, int out_size, void* d_ws, size_t ws_size,
                              hipStream_t stream) {
    const float* x      = (const float*)d_in[0];
    const int*   ei     = (const int*)d_in[1];
    const float* lin_w  = (const float*)d_in[2];
    const float* bcos_w = (const float*)d_in[3];
    const float* gamma  = (const float*)d_in[4];
    const float* beta   = (const float*)d_in[5];
    float*       y      = (float*)d_out;

    // workspace layout
    float* h       = (float*)d_ws;                          // N*64 f
    float* inv_hn  = h + (size_t)N_NODES * HID;             // N*4 f
    float* inv_w   = inv_hn + (size_t)N_NODES * HEADS;      // 64 f
    int*   deg     = (int*)(inv_w + HID);                   // N i
    int*   partial = deg + N_NODES;                         // 64 i
    int*   offsets = partial + 64;                          // N+1 i
    int*   cursor  = offsets + N_NODES + 1;                 // N i
    int*   csr_col = cursor + N_NODES;                      // E i

    const int SCAN_BLOCKS = (N_NODES + 1023) / 1024;        // 49

    h_kernel<<<1024, 256, 0, stream>>>(x, lin_w, h, inv_hn, deg);

    hist_kernel<<<(NEDGE / 4 + 255) / 256, 256, 0, stream>>>(ei, deg);

    partial_kernel<<<SCAN_BLOCKS, 1024, 0, stream>>>(deg, partial, bcos_w, inv_w);

    offsets_kernel<<<SCAN_BLOCKS, 1024, 0, stream>>>(deg, partial, offsets, cursor);

    fill_kernel<<<(NEDGE / 4 + 255) / 256, 256, 0, stream>>>(ei, cursor, csr_col);

    gather_final<<<2048, 256, 0, stream>>>(offsets, csr_col, h, inv_hn,
                                           bcos_w, inv_w, gamma, beta, y);
}